// Round 10
// baseline (82.996 us; speedup 1.0000x reference)
//
#include <hip/hip_runtime.h>
#include <cfloat>

typedef __bf16 bf16x8 __attribute__((ext_vector_type(8)));
typedef unsigned short ushort8 __attribute__((ext_vector_type(8)));
typedef float f32x16 __attribute__((ext_vector_type(16)));

#define S_SLICES 4   // 96 x 4 x 2 = 768 blocks = 3/CU resident, no tail
                     // (round 9: S=8 -> 1536 blocks vs 1024 resident -> 1.5x tail)

// fp32 -> bf16 bits, round-to-nearest-even
static __device__ __forceinline__ unsigned short f2bf(float x) {
    unsigned u = __float_as_uint(x);
    return (unsigned short)((u + 0x7FFFu + ((u >> 16) & 1u)) >> 16);
}
static __device__ __forceinline__ float bfbits2f(unsigned short h) {
    return __uint_as_float(((unsigned)h) << 16);
}

// Per point, build TWO 16-element K-vectors (verified round 7/8):
//  row vec: [-2hx,-2hy,-2hz, -2hx,-2hy,-2hz, -2lx,-2ly,-2lz, s1,s2,s3, 1,1,1, 0]
//  col vec: [ hx,  hy,  hz,   lx,  ly,  lz,   hx,  hy,  hz,  1,1,1, t1,t2,t3, 0]
//  => sum_k row[k]*col[k] = nrmRow + nrmCol - 2(hh+hl+lh) ~= d2 (err ~1e-4).
// Fragment storage: frag[tile*64 + q*32 + l5], point = tile*32+l5, k = q*8+j.
// Pad points get nrm=1e30 -> never win a min.
__global__ __launch_bounds__(256) void prep_kernel(
    const float* __restrict__ A, const float* __restrict__ B,
    ushort8* __restrict__ RFA, ushort8* __restrict__ CFA,
    ushort8* __restrict__ RFB, ushort8* __restrict__ CFB,
    float* __restrict__ hdr, int n, int m, int RTn, int RTm)
{
    const int i = blockIdx.x * 256 + threadIdx.x;
    if (i < 8) hdr[i] = 0.f;
    const unsigned short one = 0x3F80;

#pragma unroll
    for (int side = 0; side < 2; ++side) {
        const int cntPts = side ? RTm * 32 : RTn * 32;
        if (i >= cntPts) continue;
        const float* P = side ? B : A;
        const int lim = side ? m : n;
        ushort8* RF = side ? RFB : RFA;
        ushort8* CF = side ? CFB : CFA;

        float x = 0.f, y = 0.f, z = 0.f, nrm = 1e30f;
        if (i < lim) { x = P[3*i]; y = P[3*i+1]; z = P[3*i+2];
                       nrm = fmaf(x, x, fmaf(y, y, z * z)); }
        const unsigned short hx = f2bf(x), hy = f2bf(y), hz = f2bf(z);
        const unsigned short lx = f2bf(x - bfbits2f(hx)),
                             ly = f2bf(y - bfbits2f(hy)),
                             lz = f2bf(z - bfbits2f(hz));
        const unsigned short nhx = f2bf(-2.f * bfbits2f(hx)),
                             nhy = f2bf(-2.f * bfbits2f(hy)),
                             nhz = f2bf(-2.f * bfbits2f(hz));
        const unsigned short nlx = f2bf(-2.f * bfbits2f(lx)),
                             nly = f2bf(-2.f * bfbits2f(ly)),
                             nlz = f2bf(-2.f * bfbits2f(lz));
        float r = nrm;
        const unsigned short s1 = f2bf(r); r -= bfbits2f(s1);
        const unsigned short s2 = f2bf(r); r -= bfbits2f(s2);
        const unsigned short s3 = f2bf(r);

        const int t = i >> 5, l5 = i & 31;
        ushort8 rq0 = { nhx, nhy, nhz, nhx, nhy, nhz, nlx, nly };
        ushort8 rq1 = { nlz, s1, s2, s3, one, one, one, 0 };
        RF[t * 64 + l5]      = rq0;
        RF[t * 64 + 32 + l5] = rq1;
        ushort8 cq0 = { hx, hy, hz, lx, ly, lz, hx, hy };
        ushort8 cq1 = { hz, one, one, one, s1, s2, s3, 0 };
        CF[t * 64 + l5]      = cq0;
        CF[t * 64 + 32 + l5] = cq1;
    }
}

// z=0: rows=A vs cols=B -> sbuf side 0 ("mins"); z=1: transposed ("mins_seeds").
// __launch_bounds__(256,4): 128-VGPR budget so C stays in VGPRs (round 8:
// default bounds -> C in AGPRs -> 32 accvgpr moves/tile). Two C in flight.
__global__ __launch_bounds__(256, 4) void pairmin_kernel(
    const bf16x8* __restrict__ RFA, const bf16x8* __restrict__ CFA,
    const bf16x8* __restrict__ RFB, const bf16x8* __restrict__ CFB,
    float* __restrict__ sbuf, int RTn, int RTm)
{
    const int lane = threadIdx.x & 63;
    const int wave = threadIdx.x >> 6;

    const bf16x8* RF; const bf16x8* CF; float* sb; int rtCount, ctCount, stride;
    if (blockIdx.z == 0) { RF = RFA; CF = CFB; rtCount = RTn; ctCount = RTm;
                           sb = sbuf; stride = RTn * 32; }
    else                 { RF = RFB; CF = CFA; rtCount = RTm; ctCount = RTn;
                           sb = sbuf + (size_t)S_SLICES * RTn * 32;
                           stride = RTm * 32; }

    const int rt = blockIdx.x * 4 + wave;
    if (rt >= rtCount) return;                       // wave-uniform
    sb += (size_t)blockIdx.y * stride;

    const int ctPer = (ctCount + S_SLICES - 1) / S_SLICES;
    const int ctBeg = min(blockIdx.y * ctPer, ctCount);
    const int ctEnd = min(ctBeg + ctPer, ctCount);

    const bf16x8 afrag = RF[rt * 64 + lane];         // loop-invariant
    const f32x16 zc = {};                            // hoisted zero C-operand

    float macc[16];
#pragma unroll
    for (int r = 0; r < 16; ++r) macc[r] = FLT_MAX;

    if (ctBeg < ctEnd) {
        int ct = ctBeg;
        bf16x8 b0 = CF[ct * 64 + lane];
        f32x16 C0 = __builtin_amdgcn_mfma_f32_32x32x16_bf16(afrag, b0, zc, 0, 0, 0);
        ++ct;
        for (; ct + 1 < ctEnd; ct += 2) {
            const bf16x8 b1 = CF[ct * 64 + lane];
            const f32x16 C1 =
                __builtin_amdgcn_mfma_f32_32x32x16_bf16(afrag, b1, zc, 0, 0, 0);
#pragma unroll
            for (int r = 0; r < 16; ++r) macc[r] = fminf(macc[r], C0[r]);
            const bf16x8 b2 = CF[(ct + 1) * 64 + lane];
            C0 = __builtin_amdgcn_mfma_f32_32x32x16_bf16(afrag, b2, zc, 0, 0, 0);
#pragma unroll
            for (int r = 0; r < 16; ++r) macc[r] = fminf(macc[r], C1[r]);
        }
        if (ct < ctEnd) {
            const bf16x8 b1 = CF[ct * 64 + lane];
            const f32x16 C1 =
                __builtin_amdgcn_mfma_f32_32x32x16_bf16(afrag, b1, zc, 0, 0, 0);
#pragma unroll
            for (int r = 0; r < 16; ++r) macc[r] = fminf(macc[r], C0[r]);
#pragma unroll
            for (int r = 0; r < 16; ++r) macc[r] = fminf(macc[r], C1[r]);
        } else {
#pragma unroll
            for (int r = 0; r < 16; ++r) macc[r] = fminf(macc[r], C0[r]);
        }
    }

    // reduce row mins across the 32 cols held in each 32-lane half
#pragma unroll
    for (int r = 0; r < 16; ++r) {
        float v = macc[r];
        v = fminf(v, __shfl_xor(v, 1, 64));
        v = fminf(v, __shfl_xor(v, 2, 64));
        v = fminf(v, __shfl_xor(v, 4, 64));
        v = fminf(v, __shfl_xor(v, 8, 64));
        v = fminf(v, __shfl_xor(v, 16, 64));
        macc[r] = v;
    }
    if ((lane & 31) == 0) {
        const int q4 = (lane >> 5) * 4;              // C map: row=(r&3)+8*(r>>2)+4*q
        float* dst = sb + rt * 32;
#pragma unroll
        for (int r = 0; r < 16; ++r)
            dst[(r & 3) + 8 * (r >> 2) + q4] = macc[r];
    }
}

// out layout: [loss+loss_seeds, mins_seeds(m), loss, loss_seeds]
__global__ __launch_bounds__(256) void finalize_kernel(
    const float* __restrict__ sbuf, float* __restrict__ hdr,
    float* __restrict__ out, int n, int m, int RTn, int RTm)
{
    const int i = blockIdx.x * 256 + threadIdx.x;
    const int strideA = RTn * 32, strideB = RTm * 32;
    const float* sbB = sbuf + (size_t)S_SLICES * strideA;

    float sa = 0.f, sb_ = 0.f;
    if (i < n) {
        float s = FLT_MAX;
#pragma unroll
        for (int k = 0; k < S_SLICES; ++k) s = fminf(s, sbuf[(size_t)k * strideA + i]);
        sa = sqrtf(fmaxf(s, 0.f));
    }
    if (i < m) {
        float s = FLT_MAX;
#pragma unroll
        for (int k = 0; k < S_SLICES; ++k) s = fminf(s, sbB[(size_t)k * strideB + i]);
        const float v = sqrtf(fmaxf(s, 0.f));
        out[1 + i] = v;                  // mins_seeds
        sb_ = v;
    }

#pragma unroll
    for (int off = 32; off > 0; off >>= 1) {
        sa  += __shfl_down(sa,  off, 64);
        sb_ += __shfl_down(sb_, off, 64);
    }
    __shared__ float reda[4], redb[4];
    const int wave = threadIdx.x >> 6;
    const int lane = threadIdx.x & 63;
    if (lane == 0) { reda[wave] = sa; redb[wave] = sb_; }
    __syncthreads();

    if (threadIdx.x == 0) {
        const float ta = reda[0] + reda[1] + reda[2] + reda[3];
        const float tb = redb[0] + redb[1] + redb[2] + redb[3];
        atomicAdd(&hdr[0], ta);
        atomicAdd(&hdr[1], tb);
        __threadfence();
        const unsigned ticket = atomicAdd((unsigned*)&hdr[2], 1u);
        if (ticket == (unsigned)(gridDim.x - 1)) {
            const float fa = atomicAdd(&hdr[0], 0.f);
            const float fb = atomicAdd(&hdr[1], 0.f);
            const float loss = fa / (float)n;
            const float loss_seeds = fb / (float)m;
            out[0] = loss + loss_seeds;
            out[1 + m] = loss;
            out[2 + m] = loss_seeds;
        }
    }
}

extern "C" void kernel_launch(void* const* d_in, const int* in_sizes, int n_in,
                              void* d_out, int out_size, void* d_ws, size_t ws_size,
                              hipStream_t stream) {
    const int n = in_sizes[0] / 3;   // true_pos count
    const int m = in_sizes[1] / 3;   // pred_pos count
    const float* A = (const float*)d_in[0];
    const float* B = (const float*)d_in[1];
    float* out = (float*)d_out;

    const int RTn = (n + 31) / 32, RTm = (m + 31) / 32;
    char* p = (char*)d_ws;
    float*   hdr  = (float*)p;    p += 64;
    float*   sbuf = (float*)p;    p += (size_t)S_SLICES * (RTn + RTm) * 32 * 4;
    ushort8* RFA  = (ushort8*)p;  p += (size_t)RTn * 64 * 16;
    ushort8* CFA  = (ushort8*)p;  p += (size_t)RTn * 64 * 16;
    ushort8* RFB  = (ushort8*)p;  p += (size_t)RTm * 64 * 16;
    ushort8* CFB  = (ushort8*)p;

    const int maxPts = ((RTn > RTm) ? RTn : RTm) * 32;
    prep_kernel<<<(maxPts + 255) / 256, 256, 0, stream>>>(
        A, B, RFA, CFA, RFB, CFB, hdr, n, m, RTn, RTm);

    const int maxRT = (RTn > RTm) ? RTn : RTm;
    dim3 grid((maxRT + 3) / 4, S_SLICES, 2);
    pairmin_kernel<<<grid, 256, 0, stream>>>(
        (const bf16x8*)RFA, (const bf16x8*)CFA,
        (const bf16x8*)RFB, (const bf16x8*)CFB, sbuf, RTn, RTm);

    const int maxnm = (n > m) ? n : m;
    finalize_kernel<<<(maxnm + 255) / 256, 256, 0, stream>>>(
        sbuf, hdr, out, n, m, RTn, RTm);
}

// Round 11
// 77.234 us; speedup vs baseline: 1.0746x; 1.0746x over previous
//
#include <hip/hip_runtime.h>
#include <cfloat>

typedef __bf16 bf16x8 __attribute__((ext_vector_type(8)));
typedef unsigned short ushort8 __attribute__((ext_vector_type(8)));
typedef float f32x16 __attribute__((ext_vector_type(16)));

#define S_SLICES 4   // 96 x 4 x 2 = 768 blocks = 3/CU, fully resident

// fp32 -> bf16 bits, round-to-nearest-even
static __device__ __forceinline__ unsigned short f2bf(float x) {
    unsigned u = __float_as_uint(x);
    return (unsigned short)((u + 0x7FFFu + ((u >> 16) & 1u)) >> 16);
}
static __device__ __forceinline__ float bfbits2f(unsigned short h) {
    return __uint_as_float(((unsigned)h) << 16);
}

// Per point, build TWO 16-element K-vectors (verified round 7/8):
//  row vec: [-2hx,-2hy,-2hz, -2hx,-2hy,-2hz, -2lx,-2ly,-2lz, s1,s2,s3, 1,1,1, 0]
//  col vec: [ hx,  hy,  hz,   lx,  ly,  lz,   hx,  hy,  hz,  1,1,1, t1,t2,t3, 0]
//  => sum_k row[k]*col[k] = nrmRow + nrmCol - 2(hh+hl+lh) ~= d2 (err ~1e-4).
// Fragment storage: frag[tile*64 + q*32 + l5], point = tile*32+l5, k = q*8+j.
// Pad points get nrm=1e30 -> never win a min.
__global__ __launch_bounds__(256) void prep_kernel(
    const float* __restrict__ A, const float* __restrict__ B,
    ushort8* __restrict__ RFA, ushort8* __restrict__ CFA,
    ushort8* __restrict__ RFB, ushort8* __restrict__ CFB,
    float* __restrict__ hdr, int n, int m, int RTn, int RTm)
{
    const int i = blockIdx.x * 256 + threadIdx.x;
    if (i < 8) hdr[i] = 0.f;
    const unsigned short one = 0x3F80;

#pragma unroll
    for (int side = 0; side < 2; ++side) {
        const int cntPts = side ? RTm * 32 : RTn * 32;
        if (i >= cntPts) continue;
        const float* P = side ? B : A;
        const int lim = side ? m : n;
        ushort8* RF = side ? RFB : RFA;
        ushort8* CF = side ? CFB : CFA;

        float x = 0.f, y = 0.f, z = 0.f, nrm = 1e30f;
        if (i < lim) { x = P[3*i]; y = P[3*i+1]; z = P[3*i+2];
                       nrm = fmaf(x, x, fmaf(y, y, z * z)); }
        const unsigned short hx = f2bf(x), hy = f2bf(y), hz = f2bf(z);
        const unsigned short lx = f2bf(x - bfbits2f(hx)),
                             ly = f2bf(y - bfbits2f(hy)),
                             lz = f2bf(z - bfbits2f(hz));
        const unsigned short nhx = f2bf(-2.f * bfbits2f(hx)),
                             nhy = f2bf(-2.f * bfbits2f(hy)),
                             nhz = f2bf(-2.f * bfbits2f(hz));
        const unsigned short nlx = f2bf(-2.f * bfbits2f(lx)),
                             nly = f2bf(-2.f * bfbits2f(ly)),
                             nlz = f2bf(-2.f * bfbits2f(lz));
        float r = nrm;
        const unsigned short s1 = f2bf(r); r -= bfbits2f(s1);
        const unsigned short s2 = f2bf(r); r -= bfbits2f(s2);
        const unsigned short s3 = f2bf(r);

        const int t = i >> 5, l5 = i & 31;
        ushort8 rq0 = { nhx, nhy, nhz, nhx, nhy, nhz, nlx, nly };
        ushort8 rq1 = { nlz, s1, s2, s3, one, one, one, 0 };
        RF[t * 64 + l5]      = rq0;
        RF[t * 64 + 32 + l5] = rq1;
        ushort8 cq0 = { hx, hy, hz, lx, ly, lz, hx, hy };
        ushort8 cq1 = { hz, one, one, one, s1, s2, s3, 0 };
        CF[t * 64 + l5]      = cq0;
        CF[t * 64 + 32 + l5] = cq1;
    }
}

#define MINC(C)                                             \
    _Pragma("unroll")                                       \
    for (int r = 0; r < 16; ++r) macc[r] = fminf(macc[r], (C)[r]);

// z=0: rows=A vs cols=B -> sbuf side 0 ("mins"); z=1: transposed ("mins_seeds").
// Round 8 lesson: __launch_bounds__(256,4) keeps C in VGPRs (no accvgpr
// shuttling). Round 10 lesson: mfma(b) right after b's load exposes full
// vmem latency per tile -> 4-deep static prefetch queue (q0..q3) + 2 C in
// flight so every vmcnt wait has retired by use.
__global__ __launch_bounds__(256, 4) void pairmin_kernel(
    const bf16x8* __restrict__ RFA, const bf16x8* __restrict__ CFA,
    const bf16x8* __restrict__ RFB, const bf16x8* __restrict__ CFB,
    float* __restrict__ sbuf, int RTn, int RTm)
{
    const int lane = threadIdx.x & 63;
    const int wave = threadIdx.x >> 6;

    const bf16x8* RF; const bf16x8* CF; float* sb; int rtCount, ctCount, stride;
    if (blockIdx.z == 0) { RF = RFA; CF = CFB; rtCount = RTn; ctCount = RTm;
                           sb = sbuf; stride = RTn * 32; }
    else                 { RF = RFB; CF = CFA; rtCount = RTm; ctCount = RTn;
                           sb = sbuf + (size_t)S_SLICES * RTn * 32;
                           stride = RTm * 32; }

    const int rt = blockIdx.x * 4 + wave;
    if (rt >= rtCount) return;                       // wave-uniform
    sb += (size_t)blockIdx.y * stride;

    const int ctPer = (ctCount + S_SLICES - 1) / S_SLICES;
    const int ctBeg = min(blockIdx.y * ctPer, ctCount);
    const int ctEnd = min(ctBeg + ctPer, ctCount);

    const bf16x8 afrag = RF[rt * 64 + lane];         // loop-invariant
    const f32x16 zc = {};

    float macc[16];
#pragma unroll
    for (int r = 0; r < 16; ++r) macc[r] = FLT_MAX;

    if (ctBeg < ctEnd) {
        int ct = ctBeg;
        const int last = ctEnd - 1;
        // 4-deep prefetch queue (clamped in prologue; duplicates are
        // min-idempotent)
        bf16x8 q0 = CF[(size_t)ct * 64 + lane];
        bf16x8 q1 = CF[(size_t)min(ct + 1, last) * 64 + lane];
        bf16x8 q2 = CF[(size_t)min(ct + 2, last) * 64 + lane];
        bf16x8 q3 = CF[(size_t)min(ct + 3, last) * 64 + lane];
        f32x16 C0 = __builtin_amdgcn_mfma_f32_32x32x16_bf16(afrag, q0, zc, 0, 0, 0);
        f32x16 C1 = __builtin_amdgcn_mfma_f32_32x32x16_bf16(afrag, q1, zc, 0, 0, 0);

        // steady state: 4 tiles/iter; loads stay >= 2 tiles ahead of their MFMA
        for (; ct + 7 < ctEnd; ct += 4) {
            q0 = CF[(size_t)(ct + 4) * 64 + lane];
            MINC(C0);
            C0 = __builtin_amdgcn_mfma_f32_32x32x16_bf16(afrag, q2, zc, 0, 0, 0);
            q1 = CF[(size_t)(ct + 5) * 64 + lane];
            MINC(C1);
            C1 = __builtin_amdgcn_mfma_f32_32x32x16_bf16(afrag, q3, zc, 0, 0, 0);
            q2 = CF[(size_t)(ct + 6) * 64 + lane];
            MINC(C0);
            C0 = __builtin_amdgcn_mfma_f32_32x32x16_bf16(afrag, q0, zc, 0, 0, 0);
            q3 = CF[(size_t)(ct + 7) * 64 + lane];
            MINC(C1);
            C1 = __builtin_amdgcn_mfma_f32_32x32x16_bf16(afrag, q1, zc, 0, 0, 0);
        }
        // epilogue: C0/C1 hold tiles ct/ct+1 (clamped); q2/q3 hold ct+2/ct+3
        MINC(C0);
        MINC(C1);
        if (ct + 2 < ctEnd) {
            const f32x16 C =
                __builtin_amdgcn_mfma_f32_32x32x16_bf16(afrag, q2, zc, 0, 0, 0);
            MINC(C);
        }
        if (ct + 3 < ctEnd) {
            const f32x16 C =
                __builtin_amdgcn_mfma_f32_32x32x16_bf16(afrag, q3, zc, 0, 0, 0);
            MINC(C);
        }
        for (int t = ct + 4; t < ctEnd; ++t) {
            const bf16x8 b = CF[(size_t)t * 64 + lane];
            const f32x16 C =
                __builtin_amdgcn_mfma_f32_32x32x16_bf16(afrag, b, zc, 0, 0, 0);
            MINC(C);
        }
    }

    // reduce row mins across the 32 cols held in each 32-lane half
#pragma unroll
    for (int r = 0; r < 16; ++r) {
        float v = macc[r];
        v = fminf(v, __shfl_xor(v, 1, 64));
        v = fminf(v, __shfl_xor(v, 2, 64));
        v = fminf(v, __shfl_xor(v, 4, 64));
        v = fminf(v, __shfl_xor(v, 8, 64));
        v = fminf(v, __shfl_xor(v, 16, 64));
        macc[r] = v;
    }
    if ((lane & 31) == 0) {
        const int q4 = (lane >> 5) * 4;              // C map: row=(r&3)+8*(r>>2)+4*q
        float* dst = sb + rt * 32;
#pragma unroll
        for (int r = 0; r < 16; ++r)
            dst[(r & 3) + 8 * (r >> 2) + q4] = macc[r];
    }
}

// out layout: [loss+loss_seeds, mins_seeds(m), loss, loss_seeds]
__global__ __launch_bounds__(256) void finalize_kernel(
    const float* __restrict__ sbuf, float* __restrict__ hdr,
    float* __restrict__ out, int n, int m, int RTn, int RTm)
{
    const int i = blockIdx.x * 256 + threadIdx.x;
    const int strideA = RTn * 32, strideB = RTm * 32;
    const float* sbB = sbuf + (size_t)S_SLICES * strideA;

    float sa = 0.f, sb_ = 0.f;
    if (i < n) {
        float s = FLT_MAX;
#pragma unroll
        for (int k = 0; k < S_SLICES; ++k) s = fminf(s, sbuf[(size_t)k * strideA + i]);
        sa = sqrtf(fmaxf(s, 0.f));
    }
    if (i < m) {
        float s = FLT_MAX;
#pragma unroll
        for (int k = 0; k < S_SLICES; ++k) s = fminf(s, sbB[(size_t)k * strideB + i]);
        const float v = sqrtf(fmaxf(s, 0.f));
        out[1 + i] = v;                  // mins_seeds
        sb_ = v;
    }

#pragma unroll
    for (int off = 32; off > 0; off >>= 1) {
        sa  += __shfl_down(sa,  off, 64);
        sb_ += __shfl_down(sb_, off, 64);
    }
    __shared__ float reda[4], redb[4];
    const int wave = threadIdx.x >> 6;
    const int lane = threadIdx.x & 63;
    if (lane == 0) { reda[wave] = sa; redb[wave] = sb_; }
    __syncthreads();

    if (threadIdx.x == 0) {
        const float ta = reda[0] + reda[1] + reda[2] + reda[3];
        const float tb = redb[0] + redb[1] + redb[2] + redb[3];
        atomicAdd(&hdr[0], ta);
        atomicAdd(&hdr[1], tb);
        __threadfence();
        const unsigned ticket = atomicAdd((unsigned*)&hdr[2], 1u);
        if (ticket == (unsigned)(gridDim.x - 1)) {
            const float fa = atomicAdd(&hdr[0], 0.f);
            const float fb = atomicAdd(&hdr[1], 0.f);
            const float loss = fa / (float)n;
            const float loss_seeds = fb / (float)m;
            out[0] = loss + loss_seeds;
            out[1 + m] = loss;
            out[2 + m] = loss_seeds;
        }
    }
}

extern "C" void kernel_launch(void* const* d_in, const int* in_sizes, int n_in,
                              void* d_out, int out_size, void* d_ws, size_t ws_size,
                              hipStream_t stream) {
    const int n = in_sizes[0] / 3;   // true_pos count
    const int m = in_sizes[1] / 3;   // pred_pos count
    const float* A = (const float*)d_in[0];
    const float* B = (const float*)d_in[1];
    float* out = (float*)d_out;

    const int RTn = (n + 31) / 32, RTm = (m + 31) / 32;
    char* p = (char*)d_ws;
    float*   hdr  = (float*)p;    p += 64;
    float*   sbuf = (float*)p;    p += (size_t)S_SLICES * (RTn + RTm) * 32 * 4;
    ushort8* RFA  = (ushort8*)p;  p += (size_t)RTn * 64 * 16;
    ushort8* CFA  = (ushort8*)p;  p += (size_t)RTn * 64 * 16;
    ushort8* RFB  = (ushort8*)p;  p += (size_t)RTm * 64 * 16;
    ushort8* CFB  = (ushort8*)p;

    const int maxPts = ((RTn > RTm) ? RTn : RTm) * 32;
    prep_kernel<<<(maxPts + 255) / 256, 256, 0, stream>>>(
        A, B, RFA, CFA, RFB, CFB, hdr, n, m, RTn, RTm);

    const int maxRT = (RTn > RTm) ? RTn : RTm;
    dim3 grid((maxRT + 3) / 4, S_SLICES, 2);
    pairmin_kernel<<<grid, 256, 0, stream>>>(
        (const bf16x8*)RFA, (const bf16x8*)CFA,
        (const bf16x8*)RFB, (const bf16x8*)CFB, sbuf, RTn, RTm);

    const int maxnm = (n > m) ? n : m;
    finalize_kernel<<<(maxnm + 255) / 256, 256, 0, stream>>>(
        sbuf, hdr, out, n, m, RTn, RTm);
}